// Round 8
// baseline (30.329 us; speedup 1.0000x reference)
//
#include <hip/hip_runtime.h>

#define B 32
#define L 512
#define D 768
#define M 24
#define P (M * (M - 1))   // 552
#define Q4 (D / 4)        // 192 float4 per half-row

typedef float f32x4 __attribute__((ext_vector_type(4)));

// K1: one block per (b,m), 192 threads. Parallel gather (15 clamped
// unconditional loads -> all in flight at once, masked adds), writes the
// pooled vector (regular stores -> stays L2/L3 hot for K2).
__global__ void __launch_bounds__(Q4)
pool_kernel(const float* __restrict__ seq,   // B,L,D
            const int*   __restrict__ head,  // B,L
            const int*   __restrict__ em,    // B,M,2
            float*       __restrict__ pooled)// B,M,D
{
    int bm = blockIdx.x;           // 0 .. B*M-1
    int b = bm / M;
    int tq = threadIdx.x;          // 0..191

    int s = em[bm * 2 + 0];
    int e = em[bm * 2 + 1];
    int len = e - s;               // 1..15

    const float* seqb  = seq  + (size_t)b * L * D;
    const int*   headb = head + b * L;

    int hidx[15];
    #pragma unroll
    for (int r = 0; r < 15; ++r) {
        int l = s + r; l = (l < e) ? l : s;   // clamp -> unconditional
        hidx[r] = headb[l];
    }
    f32x4 vv[15];
    #pragma unroll
    for (int r = 0; r < 15; ++r)
        vv[r] = ((const f32x4*)(seqb + (size_t)hidx[r] * D))[tq];
    f32x4 acc = (f32x4)(0.f);
    #pragma unroll
    for (int r = 0; r < 15; ++r)
        acc += (r < len) ? vv[r] : (f32x4)(0.f);
    acc *= 1.0f / (float)len;

    ((f32x4*)pooled)[(size_t)bm * Q4 + tq] = acc;
}

// K2: one block per output row (B*P = 17664 blocks), 384 threads.
// Each thread: one float4 read from pooled (L2/L3-hot) + one contiguous NT
// store. Pure write-streaming kernel. Lane 0 also emits the 5-float pair row.
__global__ void __launch_bounds__(2 * Q4)
rel_kernel(const float* __restrict__ pooled,  // B,M,D
           const int*   __restrict__ em,      // B,M,2
           float*       __restrict__ out)     // B*P*1536 rel | B*P*5 pairs
{
    int bp = blockIdx.x;           // 0 .. B*P-1
    int t  = threadIdx.x;          // 0..383
    int b  = bp / P;
    int p  = bp - b * P;
    int i  = p / (M - 1);
    int r  = p - i * (M - 1);
    int j  = (r < i) ? r : r + 1;

    int src_m = (t < Q4) ? i : j;                 // wave-uniform branch
    int tq    = (t < Q4) ? t : t - Q4;
    f32x4 v = ((const f32x4*)pooled)[(size_t)(b * M + src_m) * Q4 + tq];
    __builtin_nontemporal_store(v, &((f32x4*)out)[(size_t)bp * 384 + t]);

    if (t == 0) {
        const int* emb = em + b * M * 2;
        float* o = out + (size_t)B * P * 2 * D + (size_t)bp * 5;
        o[0] = (float)b;
        o[1] = (float)emb[2 * i];
        o[2] = (float)emb[2 * i + 1];
        o[3] = (float)emb[2 * j];
        o[4] = (float)emb[2 * j + 1];
    }
}

extern "C" void kernel_launch(void* const* d_in, const int* in_sizes, int n_in,
                              void* d_out, int out_size, void* d_ws, size_t ws_size,
                              hipStream_t stream) {
    const float* seq  = (const float*)d_in[0];
    const int*   head = (const int*)d_in[1];
    const int*   em   = (const int*)d_in[2];
    float* out    = (float*)d_out;
    float* pooled = (float*)d_ws;                 // B*M*D f32 = 2.36 MB

    pool_kernel<<<B * M, Q4, 0, stream>>>(seq, head, em, pooled);
    rel_kernel<<<B * P, 2 * Q4, 0, stream>>>(pooled, em, out);
}